// Round 1
// baseline (563.908 us; speedup 1.0000x reference)
//
#include <hip/hip_runtime.h>
#include <hip/hip_bf16.h>

#define N_NODES   100000
#define N_EDGES   1000000
#define HID       64
#define NUM_GRAPHS 1024

// ---------------- CSR build ----------------

__global__ __launch_bounds__(256) void count_deg(const int* __restrict__ dst,
                                                 int* __restrict__ deg) {
    int e = blockIdx.x * 256 + threadIdx.x;
    if (e < N_EDGES) atomicAdd(&deg[dst[e]], 1);
}

__global__ __launch_bounds__(256) void node_prep(const int* __restrict__ deg,
                                                 float* __restrict__ dinv,
                                                 float* __restrict__ invd) {
    int i = blockIdx.x * 256 + threadIdx.x;
    if (i < N_NODES) {
        float df = (float)(deg[i] + 1);   // +1 self loop
        dinv[i] = rsqrtf(df);
        invd[i] = 1.0f / df;
    }
}

// inclusive scan of deg within 1024-blocks; incl -> rowst (temp), block total -> bsums
__global__ __launch_bounds__(1024) void scan1(const int* __restrict__ deg,
                                              int* __restrict__ rowst,
                                              int* __restrict__ bsums, int n) {
    __shared__ int buf[1024];
    int t = threadIdx.x, g = blockIdx.x * 1024 + t;
    int v = (g < n) ? deg[g] : 0;
    buf[t] = v;
    __syncthreads();
    #pragma unroll
    for (int off = 1; off < 1024; off <<= 1) {
        int x = (t >= off) ? buf[t - off] : 0;
        __syncthreads();
        buf[t] += x;
        __syncthreads();
    }
    if (g < n) rowst[g] = buf[t];
    if (t == 1023) bsums[blockIdx.x] = buf[1023];
}

// exclusive scan of block sums (nb <= 128), one block
__global__ __launch_bounds__(128) void scan2(int* __restrict__ bsums, int nb) {
    __shared__ int buf[128];
    int t = threadIdx.x;
    int v = (t < nb) ? bsums[t] : 0;
    buf[t] = v;
    __syncthreads();
    #pragma unroll
    for (int off = 1; off < 128; off <<= 1) {
        int x = (t >= off) ? buf[t - off] : 0;
        __syncthreads();
        buf[t] += x;
        __syncthreads();
    }
    if (t < nb) bsums[t] = buf[t] - v;   // exclusive
}

// rowst: inclusive-in-block -> global exclusive; set rowst[n] = E
__global__ __launch_bounds__(256) void scan3(const int* __restrict__ deg,
                                             int* __restrict__ rowst,
                                             const int* __restrict__ bsums, int n) {
    int g = blockIdx.x * 256 + threadIdx.x;
    if (g < n) rowst[g] = rowst[g] - deg[g] + bsums[g >> 10];
    if (g == 0) rowst[n] = N_EDGES;
}

__global__ __launch_bounds__(256) void fill_csr(const int* __restrict__ src,
                                                const int* __restrict__ dst,
                                                const int* __restrict__ rowst,
                                                int* __restrict__ cursor,
                                                const float* __restrict__ dinv,
                                                int2* __restrict__ edata) {
    int e = blockIdx.x * 256 + threadIdx.x;
    if (e >= N_EDGES) return;
    int s = src[e], d = dst[e];
    int p = rowst[d] + atomicAdd(&cursor[d], 1);
    edata[p] = make_int2(s, __float_as_int(dinv[s] * dinv[d]));
}

// ---------------- dense xw = X @ W (64x64, fp32 vector ALU) ----------------

__global__ __launch_bounds__(256) void gemm64(const float* __restrict__ X,
                                              const float* __restrict__ W,
                                              float* __restrict__ Y, int nrows) {
    __shared__ float Wl[4096];
    int t = threadIdx.x;
    #pragma unroll
    for (int i = 0; i < 4; i++) {
        int idx = (t + i * 256) * 4;
        *(float4*)(Wl + idx) = *(const float4*)(W + idx);
    }
    __syncthreads();
    int row = blockIdx.x * 256 + t;
    if (row >= nrows) return;
    const float4* xr = (const float4*)(X + (size_t)row * 64);
    float4 acc[16];
    #pragma unroll
    for (int j = 0; j < 16; j++) acc[j] = make_float4(0.f, 0.f, 0.f, 0.f);
    #pragma unroll
    for (int k4 = 0; k4 < 16; k4++) {
        float4 xv = xr[k4];
        float xk0 = xv.x, xk1 = xv.y, xk2 = xv.z, xk3 = xv.w;
        #pragma unroll
        for (int kk = 0; kk < 4; kk++) {
            float xk = (kk == 0) ? xk0 : (kk == 1) ? xk1 : (kk == 2) ? xk2 : xk3;
            const float4* wr = (const float4*)(Wl + (k4 * 4 + kk) * 64);
            #pragma unroll
            for (int j = 0; j < 16; j++) {
                float4 w = wr[j];   // all lanes same address -> LDS broadcast
                acc[j].x += xk * w.x;
                acc[j].y += xk * w.y;
                acc[j].z += xk * w.z;
                acc[j].w += xk * w.w;
            }
        }
    }
    float4* yr = (float4*)(Y + (size_t)row * 64);
    #pragma unroll
    for (int j = 0; j < 16; j++) yr[j] = acc[j];
}

// ---------------- aggregation: one wave per node, lane = channel ----------------

__global__ __launch_bounds__(256) void agg_relu(const float* __restrict__ XW,
                                                const int* __restrict__ rowst,
                                                const int2* __restrict__ edata,
                                                const float* __restrict__ invd,
                                                const float* __restrict__ bias,
                                                float* __restrict__ H) {
    int wid = (blockIdx.x * 256 + threadIdx.x) >> 6;
    int lane = threadIdx.x & 63;
    if (wid >= N_NODES) return;
    float acc = XW[(size_t)wid * 64 + lane] * invd[wid];
    int e0 = rowst[wid], e1 = rowst[wid + 1];
    for (int e = e0; e < e1; e++) {
        int2 ed = edata[e];                       // broadcast 8B
        acc += XW[(size_t)ed.x * 64 + lane] * __int_as_float(ed.y);
    }
    H[(size_t)wid * 64 + lane] = fmaxf(acc + bias[lane], 0.f);
}

// layer-2 aggregation fused with ReLU, dot(Wout) and per-graph accumulation
__global__ __launch_bounds__(256) void agg_pool(const float* __restrict__ XW,
                                                const int* __restrict__ rowst,
                                                const int2* __restrict__ edata,
                                                const float* __restrict__ invd,
                                                const float* __restrict__ bias,
                                                const float* __restrict__ Wout,
                                                const int* __restrict__ batch,
                                                float* __restrict__ outsum,
                                                int* __restrict__ cnt) {
    int wid = (blockIdx.x * 256 + threadIdx.x) >> 6;
    int lane = threadIdx.x & 63;
    if (wid >= N_NODES) return;
    float acc = XW[(size_t)wid * 64 + lane] * invd[wid];
    int e0 = rowst[wid], e1 = rowst[wid + 1];
    for (int e = e0; e < e1; e++) {
        int2 ed = edata[e];
        acc += XW[(size_t)ed.x * 64 + lane] * __int_as_float(ed.y);
    }
    float h = fmaxf(acc + bias[lane], 0.f);
    float v = h * Wout[lane];
    #pragma unroll
    for (int off = 32; off > 0; off >>= 1) v += __shfl_down(v, off, 64);
    if (lane == 0) {
        int g = batch[wid];
        atomicAdd(&outsum[g], v);
        atomicAdd(&cnt[g], 1);
    }
}

__global__ __launch_bounds__(256) void finalize(const float* __restrict__ outsum,
                                                const int* __restrict__ cnt,
                                                const float* __restrict__ bout,
                                                float* __restrict__ out) {
    int g = blockIdx.x * 256 + threadIdx.x;
    if (g < NUM_GRAPHS) {
        float c = (float)max(cnt[g], 1);
        out[g] = outsum[g] / c + bout[0];
    }
}

// ---------------- launch ----------------

extern "C" void kernel_launch(void* const* d_in, const int* in_sizes, int n_in,
                              void* d_out, int out_size, void* d_ws, size_t ws_size,
                              hipStream_t stream) {
    const float* x     = (const float*)d_in[0];
    const int*   eidx  = (const int*)d_in[1];   // [2, E]
    const int*   batch = (const int*)d_in[2];
    const float* W1    = (const float*)d_in[3];
    const float* b1    = (const float*)d_in[4];
    const float* W2    = (const float*)d_in[5];
    const float* b2    = (const float*)d_in[6];
    const float* Wout  = (const float*)d_in[7];
    const float* bout  = (const float*)d_in[8];
    float* out = (float*)d_out;

    const int* src = eidx;
    const int* dst = eidx + N_EDGES;

    // workspace layout (4-byte words)
    float* ws = (float*)d_ws;
    size_t off = 0;
    float* xw     = ws + off; off += (size_t)N_NODES * 64;   // reused for layer 2
    float* h1     = ws + off; off += (size_t)N_NODES * 64;
    int2*  edata  = (int2*)(ws + off); off += (size_t)N_EDGES * 2;
    int*   deg    = (int*)(ws + off); off += N_NODES;
    int*   rowst  = (int*)(ws + off); off += N_NODES + 4;    // padded
    int*   cursor = (int*)(ws + off); off += N_NODES;
    float* dinv   = ws + off; off += N_NODES;
    float* invd   = ws + off; off += N_NODES;
    int*   bsums  = (int*)(ws + off); off += 128;
    float* outsum = ws + off; off += NUM_GRAPHS;
    int*   cnt    = (int*)(ws + off); off += NUM_GRAPHS;

    // zero: deg .. cursor end (contiguous), and bsums .. cnt end (contiguous)
    hipMemsetAsync(deg, 0, (size_t)(3 * N_NODES + 4) * sizeof(int), stream);
    hipMemsetAsync(bsums, 0, (size_t)(128 + 2 * NUM_GRAPHS) * sizeof(int), stream);

    const int EB = (N_EDGES + 255) / 256;
    const int NB = (N_NODES + 255) / 256;
    const int SB = (N_NODES + 1023) / 1024;   // 98
    const int WB = (N_NODES * 64 + 255) / 256;

    count_deg<<<EB, 256, 0, stream>>>(dst, deg);
    node_prep<<<NB, 256, 0, stream>>>(deg, dinv, invd);
    scan1<<<SB, 1024, 0, stream>>>(deg, rowst, bsums, N_NODES);
    scan2<<<1, 128, 0, stream>>>(bsums, SB);
    scan3<<<NB, 256, 0, stream>>>(deg, rowst, bsums, N_NODES);
    fill_csr<<<EB, 256, 0, stream>>>(src, dst, rowst, cursor, dinv, edata);

    // layer 1
    gemm64<<<NB, 256, 0, stream>>>(x, W1, xw, N_NODES);
    agg_relu<<<WB, 256, 0, stream>>>(xw, rowst, edata, invd, b1, h1);
    // layer 2 (xw buffer reused)
    gemm64<<<NB, 256, 0, stream>>>(h1, W2, xw, N_NODES);
    agg_pool<<<WB, 256, 0, stream>>>(xw, rowst, edata, invd, b2, Wout, batch,
                                     outsum, cnt);
    finalize<<<(NUM_GRAPHS + 255) / 256, 256, 0, stream>>>(outsum, cnt, bout, out);
}

// Round 2
// 441.962 us; speedup vs baseline: 1.2759x; 1.2759x over previous
//
#include <hip/hip_runtime.h>
#include <hip/hip_bf16.h>

#define N_NODES   100000
#define N_EDGES   1000000
#define HID       64
#define NUM_GRAPHS 1024

// ---------------- CSR build ----------------

__global__ __launch_bounds__(256) void count_deg(const int* __restrict__ dst,
                                                 int* __restrict__ deg) {
    int e = blockIdx.x * 256 + threadIdx.x;
    if (e < N_EDGES) atomicAdd(&deg[dst[e]], 1);
}

__global__ __launch_bounds__(256) void node_prep(const int* __restrict__ deg,
                                                 float* __restrict__ dinv,
                                                 float* __restrict__ invd) {
    int i = blockIdx.x * 256 + threadIdx.x;
    if (i < N_NODES) {
        float df = (float)(deg[i] + 1);   // +1 self loop
        dinv[i] = rsqrtf(df);
        invd[i] = 1.0f / df;
    }
}

// inclusive scan of deg within 1024-blocks; incl -> rowst (temp), block total -> bsums
__global__ __launch_bounds__(1024) void scan1(const int* __restrict__ deg,
                                              int* __restrict__ rowst,
                                              int* __restrict__ bsums, int n) {
    __shared__ int buf[1024];
    int t = threadIdx.x, g = blockIdx.x * 1024 + t;
    int v = (g < n) ? deg[g] : 0;
    buf[t] = v;
    __syncthreads();
    #pragma unroll
    for (int off = 1; off < 1024; off <<= 1) {
        int x = (t >= off) ? buf[t - off] : 0;
        __syncthreads();
        buf[t] += x;
        __syncthreads();
    }
    if (g < n) rowst[g] = buf[t];
    if (t == 1023) bsums[blockIdx.x] = buf[1023];
}

// exclusive scan of block sums (nb <= 128), one block
__global__ __launch_bounds__(128) void scan2(int* __restrict__ bsums, int nb) {
    __shared__ int buf[128];
    int t = threadIdx.x;
    int v = (t < nb) ? bsums[t] : 0;
    buf[t] = v;
    __syncthreads();
    #pragma unroll
    for (int off = 1; off < 128; off <<= 1) {
        int x = (t >= off) ? buf[t - off] : 0;
        __syncthreads();
        buf[t] += x;
        __syncthreads();
    }
    if (t < nb) bsums[t] = buf[t] - v;   // exclusive
}

// rowst: inclusive-in-block -> global exclusive; set rowst[n] = E
__global__ __launch_bounds__(256) void scan3(const int* __restrict__ deg,
                                             int* __restrict__ rowst,
                                             const int* __restrict__ bsums, int n) {
    int g = blockIdx.x * 256 + threadIdx.x;
    if (g < n) rowst[g] = rowst[g] - deg[g] + bsums[g >> 10];
    if (g == 0) rowst[n] = N_EDGES;
}

__global__ __launch_bounds__(256) void fill_csr(const int* __restrict__ src,
                                                const int* __restrict__ dst,
                                                const int* __restrict__ rowst,
                                                int* __restrict__ cursor,
                                                const float* __restrict__ dinv,
                                                int2* __restrict__ edata) {
    int e = blockIdx.x * 256 + threadIdx.x;
    if (e >= N_EDGES) return;
    int s = src[e], d = dst[e];
    int p = rowst[d] + atomicAdd(&cursor[d], 1);
    edata[p] = make_int2(s, __float_as_int(dinv[s] * dinv[d]));
}

// ---------------- dense xw = X @ W (64x64, fp32 vector ALU) ----------------

__global__ __launch_bounds__(256) void gemm64(const float* __restrict__ X,
                                              const float* __restrict__ W,
                                              float* __restrict__ Y, int nrows) {
    __shared__ float Wl[4096];
    int t = threadIdx.x;
    #pragma unroll
    for (int i = 0; i < 4; i++) {
        int idx = (t + i * 256) * 4;
        *(float4*)(Wl + idx) = *(const float4*)(W + idx);
    }
    __syncthreads();
    int row = blockIdx.x * 256 + t;
    if (row >= nrows) return;
    const float4* xr = (const float4*)(X + (size_t)row * 64);
    float4 acc[16];
    #pragma unroll
    for (int j = 0; j < 16; j++) acc[j] = make_float4(0.f, 0.f, 0.f, 0.f);
    #pragma unroll
    for (int k4 = 0; k4 < 16; k4++) {
        float4 xv = xr[k4];
        float xk0 = xv.x, xk1 = xv.y, xk2 = xv.z, xk3 = xv.w;
        #pragma unroll
        for (int kk = 0; kk < 4; kk++) {
            float xk = (kk == 0) ? xk0 : (kk == 1) ? xk1 : (kk == 2) ? xk2 : xk3;
            const float4* wr = (const float4*)(Wl + (k4 * 4 + kk) * 64);
            #pragma unroll
            for (int j = 0; j < 16; j++) {
                float4 w = wr[j];   // all lanes same address -> LDS broadcast
                acc[j].x += xk * w.x;
                acc[j].y += xk * w.y;
                acc[j].z += xk * w.z;
                acc[j].w += xk * w.w;
            }
        }
    }
    float4* yr = (float4*)(Y + (size_t)row * 64);
    #pragma unroll
    for (int j = 0; j < 16; j++) yr[j] = acc[j];
}

// ---------------- aggregation: one wave per node, lane = channel ----------------
// Edge list for the node is loaded lane-parallel (one coalesced load per 64
// edges), then broadcast per-edge via __shfl. Row gathers are 8-way unrolled
// (clamped tail indices -> L1-hit dup loads, norm zeroed) for high MLP.

__device__ __forceinline__ float agg_edges(const float* __restrict__ XW,
                                           const int2* __restrict__ edata,
                                           int e0, int deg, int lane) {
    float acc = 0.f;
    for (int base = 0; base < deg; base += 64) {
        int m = deg - base;
        if (m > 64) m = 64;
        int2 ed = (lane < m) ? edata[e0 + base + lane] : make_int2(0, 0);
        int   srcs = ed.x;
        float norm = __int_as_float(ed.y);
        for (int j = 0; j < m; j += 8) {
            int   s[8];
            float nn[8];
            #pragma unroll
            for (int u = 0; u < 8; u++) {
                int jj = j + u;
                int jc = (jj < m) ? jj : (m - 1);
                s[u]  = __shfl(srcs, jc, 64);
                float nv = __shfl(norm, jc, 64);
                nn[u] = (jj < m) ? nv : 0.f;
            }
            float v[8];
            #pragma unroll
            for (int u = 0; u < 8; u++) v[u] = XW[(size_t)s[u] * 64 + lane];
            #pragma unroll
            for (int u = 0; u < 8; u++) acc += v[u] * nn[u];
        }
    }
    return acc;
}

__global__ __launch_bounds__(256) void agg_relu(const float* __restrict__ XW,
                                                const int* __restrict__ rowst,
                                                const int2* __restrict__ edata,
                                                const float* __restrict__ invd,
                                                const float* __restrict__ bias,
                                                float* __restrict__ H) {
    int wid = (blockIdx.x * 256 + threadIdx.x) >> 6;
    int lane = threadIdx.x & 63;
    if (wid >= N_NODES) return;
    int e0 = rowst[wid], e1 = rowst[wid + 1];
    float acc = XW[(size_t)wid * 64 + lane] * invd[wid];
    acc += agg_edges(XW, edata, e0, e1 - e0, lane);
    H[(size_t)wid * 64 + lane] = fmaxf(acc + bias[lane], 0.f);
}

// layer-2 aggregation fused with ReLU, dot(Wout) and per-graph accumulation
__global__ __launch_bounds__(256) void agg_pool(const float* __restrict__ XW,
                                                const int* __restrict__ rowst,
                                                const int2* __restrict__ edata,
                                                const float* __restrict__ invd,
                                                const float* __restrict__ bias,
                                                const float* __restrict__ Wout,
                                                const int* __restrict__ batch,
                                                float* __restrict__ outsum,
                                                int* __restrict__ cnt) {
    int wid = (blockIdx.x * 256 + threadIdx.x) >> 6;
    int lane = threadIdx.x & 63;
    if (wid >= N_NODES) return;
    int e0 = rowst[wid], e1 = rowst[wid + 1];
    float acc = XW[(size_t)wid * 64 + lane] * invd[wid];
    acc += agg_edges(XW, edata, e0, e1 - e0, lane);
    float h = fmaxf(acc + bias[lane], 0.f);
    float v = h * Wout[lane];
    #pragma unroll
    for (int off = 32; off > 0; off >>= 1) v += __shfl_down(v, off, 64);
    if (lane == 0) {
        int g = batch[wid];
        atomicAdd(&outsum[g], v);
        atomicAdd(&cnt[g], 1);
    }
}

__global__ __launch_bounds__(256) void finalize(const float* __restrict__ outsum,
                                                const int* __restrict__ cnt,
                                                const float* __restrict__ bout,
                                                float* __restrict__ out) {
    int g = blockIdx.x * 256 + threadIdx.x;
    if (g < NUM_GRAPHS) {
        float c = (float)max(cnt[g], 1);
        out[g] = outsum[g] / c + bout[0];
    }
}

// ---------------- launch ----------------

extern "C" void kernel_launch(void* const* d_in, const int* in_sizes, int n_in,
                              void* d_out, int out_size, void* d_ws, size_t ws_size,
                              hipStream_t stream) {
    const float* x     = (const float*)d_in[0];
    const int*   eidx  = (const int*)d_in[1];   // [2, E]
    const int*   batch = (const int*)d_in[2];
    const float* W1    = (const float*)d_in[3];
    const float* b1    = (const float*)d_in[4];
    const float* W2    = (const float*)d_in[5];
    const float* b2    = (const float*)d_in[6];
    const float* Wout  = (const float*)d_in[7];
    const float* bout  = (const float*)d_in[8];
    float* out = (float*)d_out;

    const int* src = eidx;
    const int* dst = eidx + N_EDGES;

    // workspace layout (4-byte words)
    float* ws = (float*)d_ws;
    size_t off = 0;
    float* xw     = ws + off; off += (size_t)N_NODES * 64;   // reused for layer 2
    float* h1     = ws + off; off += (size_t)N_NODES * 64;
    int2*  edata  = (int2*)(ws + off); off += (size_t)N_EDGES * 2;
    int*   deg    = (int*)(ws + off); off += N_NODES;
    int*   rowst  = (int*)(ws + off); off += N_NODES + 4;    // padded
    int*   cursor = (int*)(ws + off); off += N_NODES;
    float* dinv   = ws + off; off += N_NODES;
    float* invd   = ws + off; off += N_NODES;
    int*   bsums  = (int*)(ws + off); off += 128;
    float* outsum = ws + off; off += NUM_GRAPHS;
    int*   cnt    = (int*)(ws + off); off += NUM_GRAPHS;

    // zero: deg .. cursor end (contiguous), and bsums .. cnt end (contiguous)
    hipMemsetAsync(deg, 0, (size_t)(3 * N_NODES + 4) * sizeof(int), stream);
    hipMemsetAsync(bsums, 0, (size_t)(128 + 2 * NUM_GRAPHS) * sizeof(int), stream);

    const int EB = (N_EDGES + 255) / 256;
    const int NB = (N_NODES + 255) / 256;
    const int SB = (N_NODES + 1023) / 1024;   // 98
    const int WB = (N_NODES * 64 + 255) / 256;

    count_deg<<<EB, 256, 0, stream>>>(dst, deg);
    node_prep<<<NB, 256, 0, stream>>>(deg, dinv, invd);
    scan1<<<SB, 1024, 0, stream>>>(deg, rowst, bsums, N_NODES);
    scan2<<<1, 128, 0, stream>>>(bsums, SB);
    scan3<<<NB, 256, 0, stream>>>(deg, rowst, bsums, N_NODES);
    fill_csr<<<EB, 256, 0, stream>>>(src, dst, rowst, cursor, dinv, edata);

    // layer 1
    gemm64<<<NB, 256, 0, stream>>>(x, W1, xw, N_NODES);
    agg_relu<<<WB, 256, 0, stream>>>(xw, rowst, edata, invd, b1, h1);
    // layer 2 (xw buffer reused)
    gemm64<<<NB, 256, 0, stream>>>(h1, W2, xw, N_NODES);
    agg_pool<<<WB, 256, 0, stream>>>(xw, rowst, edata, invd, b2, Wout, batch,
                                     outsum, cnt);
    finalize<<<(NUM_GRAPHS + 255) / 256, 256, 0, stream>>>(outsum, cnt, bout, out);
}

// Round 3
// 373.524 us; speedup vs baseline: 1.5097x; 1.1832x over previous
//
#include <hip/hip_runtime.h>
#include <hip/hip_bf16.h>

#define N_NODES   100000
#define N_EDGES   1000000
#define HID       64
#define NUM_GRAPHS 1024
#define NREP      8   // outsum atomic replicas

// ---------------- CSR build ----------------

__global__ __launch_bounds__(256) void count_deg(const int* __restrict__ dst,
                                                 int* __restrict__ deg) {
    int e = blockIdx.x * 256 + threadIdx.x;
    if (e < N_EDGES) atomicAdd(&deg[dst[e]], 1);
}

__global__ __launch_bounds__(256) void node_prep(const int* __restrict__ deg,
                                                 float* __restrict__ dinv,
                                                 float* __restrict__ invd) {
    int i = blockIdx.x * 256 + threadIdx.x;
    if (i < N_NODES) {
        float df = (float)(deg[i] + 1);   // +1 self loop
        dinv[i] = rsqrtf(df);
        invd[i] = 1.0f / df;
    }
}

// inclusive scan of deg within 1024-blocks; incl -> rowst (temp), block total -> bsums
__global__ __launch_bounds__(1024) void scan1(const int* __restrict__ deg,
                                              int* __restrict__ rowst,
                                              int* __restrict__ bsums, int n) {
    __shared__ int buf[1024];
    int t = threadIdx.x, g = blockIdx.x * 1024 + t;
    int v = (g < n) ? deg[g] : 0;
    buf[t] = v;
    __syncthreads();
    #pragma unroll
    for (int off = 1; off < 1024; off <<= 1) {
        int x = (t >= off) ? buf[t - off] : 0;
        __syncthreads();
        buf[t] += x;
        __syncthreads();
    }
    if (g < n) rowst[g] = buf[t];
    if (t == 1023) bsums[blockIdx.x] = buf[1023];
}

__global__ __launch_bounds__(128) void scan2(int* __restrict__ bsums, int nb) {
    __shared__ int buf[128];
    int t = threadIdx.x;
    int v = (t < nb) ? bsums[t] : 0;
    buf[t] = v;
    __syncthreads();
    #pragma unroll
    for (int off = 1; off < 128; off <<= 1) {
        int x = (t >= off) ? buf[t - off] : 0;
        __syncthreads();
        buf[t] += x;
        __syncthreads();
    }
    if (t < nb) bsums[t] = buf[t] - v;   // exclusive
}

__global__ __launch_bounds__(256) void scan3(const int* __restrict__ deg,
                                             int* __restrict__ rowst,
                                             const int* __restrict__ bsums, int n) {
    int g = blockIdx.x * 256 + threadIdx.x;
    if (g < n) rowst[g] = rowst[g] - deg[g] + bsums[g >> 10];
    if (g == 0) rowst[n] = N_EDGES;
}

__global__ __launch_bounds__(256) void fill_csr(const int* __restrict__ src,
                                                const int* __restrict__ dst,
                                                const int* __restrict__ rowst,
                                                int* __restrict__ cursor,
                                                const float* __restrict__ dinv,
                                                int2* __restrict__ edata) {
    int e = blockIdx.x * 256 + threadIdx.x;
    if (e >= N_EDGES) return;
    int s = src[e], d = dst[e];
    int p = rowst[d] + atomicAdd(&cursor[d], 1);
    edata[p] = make_int2(s, __float_as_int(dinv[s] * dinv[d]));
}

// ---------------- dense xw = X @ W (64x64, fp32 vector ALU) ----------------

__global__ __launch_bounds__(256) void gemm64(const float* __restrict__ X,
                                              const float* __restrict__ W,
                                              float* __restrict__ Y, int nrows) {
    __shared__ float Wl[4096];
    int t = threadIdx.x;
    #pragma unroll
    for (int i = 0; i < 4; i++) {
        int idx = (t + i * 256) * 4;
        *(float4*)(Wl + idx) = *(const float4*)(W + idx);
    }
    __syncthreads();
    int row = blockIdx.x * 256 + t;
    if (row >= nrows) return;
    const float4* xr = (const float4*)(X + (size_t)row * 64);
    float4 acc[16];
    #pragma unroll
    for (int j = 0; j < 16; j++) acc[j] = make_float4(0.f, 0.f, 0.f, 0.f);
    #pragma unroll
    for (int k4 = 0; k4 < 16; k4++) {
        float4 xv = xr[k4];
        #pragma unroll
        for (int kk = 0; kk < 4; kk++) {
            float xk = (kk == 0) ? xv.x : (kk == 1) ? xv.y : (kk == 2) ? xv.z : xv.w;
            const float4* wr = (const float4*)(Wl + (k4 * 4 + kk) * 64);
            #pragma unroll
            for (int j = 0; j < 16; j++) {
                float4 w = wr[j];   // LDS broadcast
                acc[j].x += xk * w.x;
                acc[j].y += xk * w.y;
                acc[j].z += xk * w.z;
                acc[j].w += xk * w.w;
            }
        }
    }
    float4* yr = (float4*)(Y + (size_t)row * 64);
    #pragma unroll
    for (int j = 0; j < 16; j++) yr[j] = acc[j];
}

// ---------------- aggregation: one wave per node, lane = channel ----------------
// Edge metadata is wave-uniform -> scalar pipe (readfirstlane -> s_load /
// broadcast). Per 16-edge group: 16 independent metadata loads, then 16
// independent row gathers (SGPR base + lane*4), then FMAs. Tail via scalar
// index clamp (dup gathers hit L1, norm=0). No shfl, no per-lane masking.

__device__ __forceinline__ float agg_edges(const float* __restrict__ XW,
                                           const int2* __restrict__ edata,
                                           int e0, int deg, int lane) {
    float acc = 0.f;
    for (int j = 0; j < deg; j += 16) {
        int2 eds[16];
        #pragma unroll
        for (int u = 0; u < 16; u++) {
            int idx = j + u;
            int ic = idx < deg ? idx : deg - 1;   // uniform clamp (s_cselect)
            eds[u] = edata[e0 + ic];
        }
        float vv[16], nn[16];
        #pragma unroll
        for (int u = 0; u < 16; u++) {
            int s = __builtin_amdgcn_readfirstlane(eds[u].x);
            nn[u] = (j + u) < deg
                  ? __int_as_float(__builtin_amdgcn_readfirstlane(eds[u].y))
                  : 0.f;
            vv[u] = XW[(size_t)s * 64 + lane];
        }
        #pragma unroll
        for (int u = 0; u < 16; u++) acc = fmaf(vv[u], nn[u], acc);
    }
    return acc;
}

__global__ __launch_bounds__(256) void agg_relu(const float* __restrict__ XW,
                                                const int* __restrict__ rowst,
                                                const int2* __restrict__ edata,
                                                const float* __restrict__ invd,
                                                const float* __restrict__ bias,
                                                float* __restrict__ H) {
    int lane = threadIdx.x & 63;
    int wid = __builtin_amdgcn_readfirstlane(blockIdx.x * 4 + (threadIdx.x >> 6));
    if (wid >= N_NODES) return;
    int e0  = __builtin_amdgcn_readfirstlane(rowst[wid]);
    int e1  = __builtin_amdgcn_readfirstlane(rowst[wid + 1]);
    float sw = __int_as_float(__builtin_amdgcn_readfirstlane(__float_as_int(invd[wid])));
    float acc = XW[(size_t)wid * 64 + lane] * sw;
    acc += agg_edges(XW, edata, e0, e1 - e0, lane);
    H[(size_t)wid * 64 + lane] = fmaxf(acc + bias[lane], 0.f);
}

__global__ __launch_bounds__(256) void agg_pool(const float* __restrict__ XW,
                                                const int* __restrict__ rowst,
                                                const int2* __restrict__ edata,
                                                const float* __restrict__ invd,
                                                const float* __restrict__ bias,
                                                const float* __restrict__ Wout,
                                                const int* __restrict__ batch,
                                                float* __restrict__ outsum) {
    int lane = threadIdx.x & 63;
    int wid = __builtin_amdgcn_readfirstlane(blockIdx.x * 4 + (threadIdx.x >> 6));
    if (wid >= N_NODES) return;
    int e0  = __builtin_amdgcn_readfirstlane(rowst[wid]);
    int e1  = __builtin_amdgcn_readfirstlane(rowst[wid + 1]);
    float sw = __int_as_float(__builtin_amdgcn_readfirstlane(__float_as_int(invd[wid])));
    float acc = XW[(size_t)wid * 64 + lane] * sw;
    acc += agg_edges(XW, edata, e0, e1 - e0, lane);
    float h = fmaxf(acc + bias[lane], 0.f);
    float v = h * Wout[lane];
    #pragma unroll
    for (int off = 32; off > 0; off >>= 1) v += __shfl_down(v, off, 64);
    if (lane == 0) {
        int g = batch[wid];
        atomicAdd(&outsum[(wid & (NREP - 1)) * NUM_GRAPHS + g], v);
    }
}

__global__ __launch_bounds__(256) void finalize(const float* __restrict__ outsum,
                                                const int* __restrict__ batch,
                                                const float* __restrict__ bout,
                                                float* __restrict__ out) {
    int g = blockIdx.x * 256 + threadIdx.x;
    if (g >= NUM_GRAPHS) return;
    float s = 0.f;
    #pragma unroll
    for (int r = 0; r < NREP; r++) s += outsum[r * NUM_GRAPHS + g];
    // node count for graph g: batch is sorted ascending
    int lo = 0, hi = N_NODES;
    while (lo < hi) { int mid = (lo + hi) >> 1; if (batch[mid] <  g) lo = mid + 1; else hi = mid; }
    int lo2 = lo, hi2 = N_NODES;
    while (lo2 < hi2) { int mid = (lo2 + hi2) >> 1; if (batch[mid] <= g) lo2 = mid + 1; else hi2 = mid; }
    float c = (float)max(lo2 - lo, 1);
    out[g] = s / c + bout[0];
}

// ---------------- launch ----------------

extern "C" void kernel_launch(void* const* d_in, const int* in_sizes, int n_in,
                              void* d_out, int out_size, void* d_ws, size_t ws_size,
                              hipStream_t stream) {
    const float* x     = (const float*)d_in[0];
    const int*   eidx  = (const int*)d_in[1];   // [2, E]
    const int*   batch = (const int*)d_in[2];
    const float* W1    = (const float*)d_in[3];
    const float* b1    = (const float*)d_in[4];
    const float* W2    = (const float*)d_in[5];
    const float* b2    = (const float*)d_in[6];
    const float* Wout  = (const float*)d_in[7];
    const float* bout  = (const float*)d_in[8];
    float* out = (float*)d_out;

    const int* src = eidx;
    const int* dst = eidx + N_EDGES;

    // workspace layout (4-byte words)
    float* ws = (float*)d_ws;
    size_t off = 0;
    float* xw     = ws + off; off += (size_t)N_NODES * 64;   // reused for layer 2
    float* h1     = ws + off; off += (size_t)N_NODES * 64;
    int2*  edata  = (int2*)(ws + off); off += (size_t)N_EDGES * 2;
    int*   deg    = (int*)(ws + off); off += N_NODES;
    int*   rowst  = (int*)(ws + off); off += N_NODES + 4;    // padded
    int*   cursor = (int*)(ws + off); off += N_NODES;
    float* dinv   = ws + off; off += N_NODES;
    float* invd   = ws + off; off += N_NODES;
    int*   bsums  = (int*)(ws + off); off += 128;
    float* outsum = ws + off; off += NREP * NUM_GRAPHS;

    hipMemsetAsync(deg, 0, (size_t)(3 * N_NODES + 4) * sizeof(int), stream);
    hipMemsetAsync(bsums, 0, (size_t)(128 + NREP * NUM_GRAPHS) * sizeof(int), stream);

    const int EB = (N_EDGES + 255) / 256;
    const int NB = (N_NODES + 255) / 256;
    const int SB = (N_NODES + 1023) / 1024;   // 98
    const int AB = (N_NODES + 3) / 4;         // 4 nodes (waves) per block

    count_deg<<<EB, 256, 0, stream>>>(dst, deg);
    node_prep<<<NB, 256, 0, stream>>>(deg, dinv, invd);
    scan1<<<SB, 1024, 0, stream>>>(deg, rowst, bsums, N_NODES);
    scan2<<<1, 128, 0, stream>>>(bsums, SB);
    scan3<<<NB, 256, 0, stream>>>(deg, rowst, bsums, N_NODES);
    fill_csr<<<EB, 256, 0, stream>>>(src, dst, rowst, cursor, dinv, edata);

    // layer 1
    gemm64<<<NB, 256, 0, stream>>>(x, W1, xw, N_NODES);
    agg_relu<<<AB, 256, 0, stream>>>(xw, rowst, edata, invd, b1, h1);
    // layer 2 (xw buffer reused)
    gemm64<<<NB, 256, 0, stream>>>(h1, W2, xw, N_NODES);
    agg_pool<<<AB, 256, 0, stream>>>(xw, rowst, edata, invd, b2, Wout, batch, outsum);
    finalize<<<(NUM_GRAPHS + 255) / 256, 256, 0, stream>>>(outsum, batch, bout, out);
}

// Round 4
// 343.179 us; speedup vs baseline: 1.6432x; 1.0884x over previous
//
#include <hip/hip_runtime.h>
#include <hip/hip_bf16.h>

#define N_NODES   100000
#define N_EDGES   1000000
#define HID       64
#define NUM_GRAPHS 1024
#define NREP      8   // outsum atomic replicas

// ---------------- CSR build ----------------

__global__ __launch_bounds__(256) void count_deg(const int* __restrict__ dst,
                                                 int* __restrict__ deg) {
    int e = blockIdx.x * 256 + threadIdx.x;
    if (e < N_EDGES) atomicAdd(&deg[dst[e]], 1);
}

// per-256-block inclusive scan of deg (shuffle-based) + dinv/invd computation
__global__ __launch_bounds__(256) void scan1(const int* __restrict__ deg,
                                             int* __restrict__ rowst,
                                             int* __restrict__ bsums,
                                             float* __restrict__ dinv,
                                             float* __restrict__ invd, int n) {
    __shared__ int wsum[4];
    int t = threadIdx.x, g = blockIdx.x * 256 + t;
    int lane = t & 63, w = t >> 6;
    int d = (g < n) ? deg[g] : 0;
    if (g < n) {
        float df = (float)(d + 1);
        dinv[g] = rsqrtf(df);
        invd[g] = 1.0f / df;
    }
    int v = d;
    #pragma unroll
    for (int off = 1; off < 64; off <<= 1) {
        int u = __shfl_up(v, off, 64);
        if (lane >= off) v += u;
    }
    if (lane == 63) wsum[w] = v;
    __syncthreads();
    int add = 0;
    #pragma unroll
    for (int i = 0; i < 4; i++) if (i < w) add += wsum[i];
    v += add;
    if (g < n) rowst[g] = v;                    // inclusive within block
    if (t == 255) bsums[blockIdx.x] = v;        // block total
}

// finalize rowst: each block computes prefix of bsums itself; rowst -> exclusive
__global__ __launch_bounds__(256) void scan3(const int* __restrict__ deg,
                                             int* __restrict__ rowst,
                                             const int* __restrict__ bsums, int n) {
    __shared__ int ws[4];
    int t = threadIdx.x, g = blockIdx.x * 256 + t;
    int s = 0;
    for (int i = t; i < blockIdx.x; i += 256) s += bsums[i];
    #pragma unroll
    for (int off = 32; off > 0; off >>= 1) s += __shfl_down(s, off, 64);
    if ((t & 63) == 0) ws[t >> 6] = s;
    __syncthreads();
    int S = ws[0] + ws[1] + ws[2] + ws[3];
    if (g < n) rowst[g] = rowst[g] - deg[g] + S;
    if (g == 0) rowst[n] = N_EDGES;
}

__global__ __launch_bounds__(256) void fill_csr(const int* __restrict__ src,
                                                const int* __restrict__ dst,
                                                const int* __restrict__ rowst,
                                                int* __restrict__ cursor,
                                                const float* __restrict__ dinv,
                                                int2* __restrict__ edata) {
    int e = blockIdx.x * 256 + threadIdx.x;
    if (e >= N_EDGES) return;
    int s = src[e], d = dst[e];
    int p = rowst[d] + atomicAdd(&cursor[d], 1);
    edata[p] = make_int2(s, __float_as_int(dinv[s] * dinv[d]));
}

// ---------------- dense xw = X @ W (64x64, fp32 vector ALU) ----------------

__global__ __launch_bounds__(256) void gemm64(const float* __restrict__ X,
                                              const float* __restrict__ W,
                                              float* __restrict__ Y, int nrows) {
    __shared__ float Wl[4096];
    int t = threadIdx.x;
    #pragma unroll
    for (int i = 0; i < 4; i++) {
        int idx = (t + i * 256) * 4;
        *(float4*)(Wl + idx) = *(const float4*)(W + idx);
    }
    __syncthreads();
    int row = blockIdx.x * 256 + t;
    if (row >= nrows) return;
    const float4* xr = (const float4*)(X + (size_t)row * 64);
    float4 acc[16];
    #pragma unroll
    for (int j = 0; j < 16; j++) acc[j] = make_float4(0.f, 0.f, 0.f, 0.f);
    #pragma unroll
    for (int k4 = 0; k4 < 16; k4++) {
        float4 xv = xr[k4];
        #pragma unroll
        for (int kk = 0; kk < 4; kk++) {
            float xk = (kk == 0) ? xv.x : (kk == 1) ? xv.y : (kk == 2) ? xv.z : xv.w;
            const float4* wr = (const float4*)(Wl + (k4 * 4 + kk) * 64);
            #pragma unroll
            for (int j = 0; j < 16; j++) {
                float4 w = wr[j];   // LDS broadcast
                acc[j].x += xk * w.x;
                acc[j].y += xk * w.y;
                acc[j].z += xk * w.z;
                acc[j].w += xk * w.w;
            }
        }
    }
    float4* yr = (float4*)(Y + (size_t)row * 64);
    #pragma unroll
    for (int j = 0; j < 16; j++) yr[j] = acc[j];
}

// ---------------- aggregation: one wave per node, lane = channel ----------------
// Edge metadata wave-uniform -> scalar pipe. 16 independent gathers in flight.

__device__ __forceinline__ float agg_edges(const float* __restrict__ XW,
                                           const int2* __restrict__ edata,
                                           int e0, int deg, int lane) {
    float acc = 0.f;
    for (int j = 0; j < deg; j += 16) {
        int2 eds[16];
        #pragma unroll
        for (int u = 0; u < 16; u++) {
            int idx = j + u;
            int ic = idx < deg ? idx : deg - 1;   // uniform clamp (s_cselect)
            eds[u] = edata[e0 + ic];
        }
        float vv[16], nn[16];
        #pragma unroll
        for (int u = 0; u < 16; u++) {
            int s = __builtin_amdgcn_readfirstlane(eds[u].x);
            nn[u] = (j + u) < deg
                  ? __int_as_float(__builtin_amdgcn_readfirstlane(eds[u].y))
                  : 0.f;
            vv[u] = XW[(size_t)s * 64 + lane];
        }
        #pragma unroll
        for (int u = 0; u < 16; u++) acc = fmaf(vv[u], nn[u], acc);
    }
    return acc;
}

// layer-1 aggregation + bias + ReLU + fused (h @ W2) -> writes Y2 row.
// h[k] broadcast via v_readlane (constant lane), W2 column read from LDS.
__global__ __launch_bounds__(256) void agg_gemm_relu(const float* __restrict__ XW,
                                                     const int* __restrict__ rowst,
                                                     const int2* __restrict__ edata,
                                                     const float* __restrict__ invd,
                                                     const float* __restrict__ bias,
                                                     const float* __restrict__ W2,
                                                     float* __restrict__ Y2) {
    __shared__ float W2l[4096];
    int t = threadIdx.x;
    #pragma unroll
    for (int i = 0; i < 4; i++) {
        int idx = (t + i * 256) * 4;
        *(float4*)(W2l + idx) = *(const float4*)(W2 + idx);
    }
    __syncthreads();

    int lane = t & 63;
    int wid = __builtin_amdgcn_readfirstlane(blockIdx.x * 4 + (t >> 6));
    if (wid >= N_NODES) return;
    int e0  = __builtin_amdgcn_readfirstlane(rowst[wid]);
    int e1  = __builtin_amdgcn_readfirstlane(rowst[wid + 1]);
    float sw = __int_as_float(__builtin_amdgcn_readfirstlane(__float_as_int(invd[wid])));
    float acc = XW[(size_t)wid * 64 + lane] * sw;
    acc += agg_edges(XW, edata, e0, e1 - e0, lane);
    float h = fmaxf(acc + bias[lane], 0.f);

    // y[lane] = sum_k h[k] * W2[k][lane]
    float y = 0.f;
    #pragma unroll
    for (int k = 0; k < 64; k++) {
        float hk = __int_as_float(__builtin_amdgcn_readlane(__float_as_int(h), k));
        y = fmaf(hk, W2l[k * 64 + lane], y);
    }
    Y2[(size_t)wid * 64 + lane] = y;
}

__global__ __launch_bounds__(256) void agg_pool(const float* __restrict__ XW,
                                                const int* __restrict__ rowst,
                                                const int2* __restrict__ edata,
                                                const float* __restrict__ invd,
                                                const float* __restrict__ bias,
                                                const float* __restrict__ Wout,
                                                const int* __restrict__ batch,
                                                float* __restrict__ outsum) {
    int lane = threadIdx.x & 63;
    int wid = __builtin_amdgcn_readfirstlane(blockIdx.x * 4 + (threadIdx.x >> 6));
    if (wid >= N_NODES) return;
    int e0  = __builtin_amdgcn_readfirstlane(rowst[wid]);
    int e1  = __builtin_amdgcn_readfirstlane(rowst[wid + 1]);
    float sw = __int_as_float(__builtin_amdgcn_readfirstlane(__float_as_int(invd[wid])));
    float acc = XW[(size_t)wid * 64 + lane] * sw;
    acc += agg_edges(XW, edata, e0, e1 - e0, lane);
    float h = fmaxf(acc + bias[lane], 0.f);
    float v = h * Wout[lane];
    #pragma unroll
    for (int off = 32; off > 0; off >>= 1) v += __shfl_down(v, off, 64);
    if (lane == 0) {
        int g = batch[wid];
        atomicAdd(&outsum[(wid & (NREP - 1)) * NUM_GRAPHS + g], v);
    }
}

__global__ __launch_bounds__(256) void finalize(const float* __restrict__ outsum,
                                                const int* __restrict__ batch,
                                                const float* __restrict__ bout,
                                                float* __restrict__ out) {
    int g = blockIdx.x * 256 + threadIdx.x;
    if (g >= NUM_GRAPHS) return;
    float s = 0.f;
    #pragma unroll
    for (int r = 0; r < NREP; r++) s += outsum[r * NUM_GRAPHS + g];
    int lo = 0, hi = N_NODES;
    while (lo < hi) { int mid = (lo + hi) >> 1; if (batch[mid] <  g) lo = mid + 1; else hi = mid; }
    int lo2 = lo, hi2 = N_NODES;
    while (lo2 < hi2) { int mid = (lo2 + hi2) >> 1; if (batch[mid] <= g) lo2 = mid + 1; else hi2 = mid; }
    float c = (float)max(lo2 - lo, 1);
    out[g] = s / c + bout[0];
}

// ---------------- launch ----------------

extern "C" void kernel_launch(void* const* d_in, const int* in_sizes, int n_in,
                              void* d_out, int out_size, void* d_ws, size_t ws_size,
                              hipStream_t stream) {
    const float* x     = (const float*)d_in[0];
    const int*   eidx  = (const int*)d_in[1];   // [2, E]
    const int*   batch = (const int*)d_in[2];
    const float* W1    = (const float*)d_in[3];
    const float* b1    = (const float*)d_in[4];
    const float* W2    = (const float*)d_in[5];
    const float* b2    = (const float*)d_in[6];
    const float* Wout  = (const float*)d_in[7];
    const float* bout  = (const float*)d_in[8];
    float* out = (float*)d_out;

    const int* src = eidx;
    const int* dst = eidx + N_EDGES;

    // workspace layout (4-byte words)
    float* ws = (float*)d_ws;
    size_t off = 0;
    float* xw     = ws + off; off += (size_t)N_NODES * 64;   // layer-1 gemm out
    float* y2     = ws + off; off += (size_t)N_NODES * 64;   // fused kernel out
    int2*  edata  = (int2*)(ws + off); off += (size_t)N_EDGES * 2;
    int*   deg    = (int*)(ws + off); off += N_NODES;
    int*   rowst  = (int*)(ws + off); off += N_NODES + 4;    // padded
    int*   cursor = (int*)(ws + off); off += N_NODES;
    float* dinv   = ws + off; off += N_NODES;
    float* invd   = ws + off; off += N_NODES;
    int*   bsums  = (int*)(ws + off); off += 512;
    float* outsum = ws + off; off += NREP * NUM_GRAPHS;

    hipMemsetAsync(deg, 0, (size_t)(3 * N_NODES + 4) * sizeof(int), stream);
    hipMemsetAsync(bsums, 0, (size_t)(512 + NREP * NUM_GRAPHS) * sizeof(int), stream);

    const int EB = (N_EDGES + 255) / 256;
    const int NB = (N_NODES + 255) / 256;   // 391 (also scan blocks)
    const int AB = (N_NODES + 3) / 4;       // 4 nodes (waves) per block

    count_deg<<<EB, 256, 0, stream>>>(dst, deg);
    scan1<<<NB, 256, 0, stream>>>(deg, rowst, bsums, dinv, invd, N_NODES);
    scan3<<<NB, 256, 0, stream>>>(deg, rowst, bsums, N_NODES);
    fill_csr<<<EB, 256, 0, stream>>>(src, dst, rowst, cursor, dinv, edata);

    gemm64<<<NB, 256, 0, stream>>>(x, W1, xw, N_NODES);
    agg_gemm_relu<<<AB, 256, 0, stream>>>(xw, rowst, edata, invd, b1, W2, y2);
    agg_pool<<<AB, 256, 0, stream>>>(y2, rowst, edata, invd, b2, Wout, batch, outsum);
    finalize<<<(NUM_GRAPHS + 255) / 256, 256, 0, stream>>>(outsum, batch, bout, out);
}